// Round 4
// baseline (473.349 us; speedup 1.0000x reference)
//
#include <hip/hip_runtime.h>

// Problem constants: B=16, P=1024, E=1024, H=16, DH=64
#define PB 16
#define PP 1024
#define PE 1024
#define PH 16
#define PDH 64

typedef __attribute__((ext_vector_type(8))) short bf16x8;
typedef __attribute__((ext_vector_type(4))) short bf16x4;
typedef __attribute__((ext_vector_type(4))) float f32x4;

__device__ __forceinline__ short f2bf(float f) {
    union { float f; unsigned u; } a;
    a.f = f;
    unsigned u = a.u;
    u += 0x7fffu + ((u >> 16) & 1u);   // round-to-nearest-even
    return (short)(u >> 16);
}
__device__ __forceinline__ float bf2f(short s) {
    union { unsigned u; float f; } a;
    a.u = ((unsigned)(unsigned short)s) << 16;
    return a.f;
}
// async global->LDS, 16B per lane; LDS dest = wave-uniform base + lane*16
__device__ __forceinline__ void async16(const void* g, void* l) {
    __builtin_amdgcn_global_load_lds(
        (const __attribute__((address_space(1))) unsigned int*)g,
        (__attribute__((address_space(3))) unsigned int*)l, 16, 0, 0);
}

// ---------------------------------------------------------------------------
// Kernel 0: fp32 -> bf16 conversions (bias [16M], wv_w [1M], out_w [1M]).
// NO transpose needed: S^T formulation wants bias in original [h][q][kv] order.
// 2048 elements per block.
// ---------------------------------------------------------------------------
__global__ __launch_bounds__(256) void conv_all(const float* __restrict__ bias,
                                                const float* __restrict__ wvw,
                                                const float* __restrict__ outw,
                                                short* __restrict__ biasB,
                                                short* __restrict__ wvwb,
                                                short* __restrict__ outwb) {
    int bid = blockIdx.x;
    const float* src;
    short* dst;
    size_t off;
    if (bid < 8192)      { src = bias; dst = biasB;  off = (size_t)bid * 2048; }
    else if (bid < 8704) { src = wvw;  dst = wvwb;   off = (size_t)(bid - 8192) * 2048; }
    else                 { src = outw; dst = outwb;  off = (size_t)(bid - 8704) * 2048; }
    size_t idx = off + (size_t)threadIdx.x * 8;
    float4 a = *(const float4*)(src + idx);
    float4 b = *(const float4*)(src + idx + 4);
    bf16x8 t = {f2bf(a.x), f2bf(a.y), f2bf(a.z), f2bf(a.w),
                f2bf(b.x), f2bf(b.y), f2bf(b.z), f2bf(b.w)};
    *(bf16x8*)(dst + idx) = t;
}

// ---------------------------------------------------------------------------
// Kernel 1: xw = (x_h @ w_att_val[h]) * 0.125 (bf16)  AND  xbf = bf16(x)
// ---------------------------------------------------------------------------
__global__ __launch_bounds__(256) void xw_kernel(const float* __restrict__ x,
                                                 const float* __restrict__ watt,
                                                 short* __restrict__ xw,
                                                 short* __restrict__ xbf) {
    int bid = blockIdx.x;
    int q4 = bid & 3;
    int bh = bid >> 2;          // b*16 + h
    int h = bh & 15;
    __shared__ short Wt[64][88];   // W^T: Wt[e'][d]

    int tid = threadIdx.x;
    {
        const float* W = watt + (size_t)h * 4096;
        int idx = tid * 16;
        int d = idx >> 6, e0 = idx & 63;
#pragma unroll
        for (int i = 0; i < 16; i += 4) {
            float4 v = *(const float4*)(W + d * 64 + e0 + i);
            Wt[e0 + i + 0][d] = f2bf(v.x);
            Wt[e0 + i + 1][d] = f2bf(v.y);
            Wt[e0 + i + 2][d] = f2bf(v.z);
            Wt[e0 + i + 3][d] = f2bf(v.w);
        }
    }
    __syncthreads();

    int wave = tid >> 6, lane = tid & 63;
    int lm = lane & 15, lq = lane >> 4;

    bf16x8 bfr[4][2];
#pragma unroll
    for (int nt = 0; nt < 4; nt++)
#pragma unroll
        for (int kf = 0; kf < 2; kf++)
            bfr[nt][kf] = *(const bf16x8*)&Wt[nt * 16 + lm][kf * 32 + lq * 8];

    int b = bh >> 4;
    for (int pass = 0; pass < 4; pass++) {
        int p0 = q4 * 256 + pass * 64 + wave * 16;
        const float* xrow = x + ((size_t)(b * 1024 + p0 + lm)) * 1024 + h * 64;
        short* xorow = xbf + ((size_t)(b * 1024 + p0 + lm)) * 1024 + h * 64;
        bf16x8 af[2];
#pragma unroll
        for (int kf = 0; kf < 2; kf++) {
            float4 v0 = *(const float4*)(xrow + kf * 32 + lq * 8);
            float4 v1 = *(const float4*)(xrow + kf * 32 + lq * 8 + 4);
            bf16x8 t;
            t[0] = f2bf(v0.x); t[1] = f2bf(v0.y); t[2] = f2bf(v0.z); t[3] = f2bf(v0.w);
            t[4] = f2bf(v1.x); t[5] = f2bf(v1.y); t[6] = f2bf(v1.z); t[7] = f2bf(v1.w);
            af[kf] = t;
            *(bf16x8*)(xorow + kf * 32 + lq * 8) = t;   // bf16 copy of x
        }
#pragma unroll
        for (int nt = 0; nt < 4; nt++) {
            f32x4 acc = {0.f, 0.f, 0.f, 0.f};
            acc = __builtin_amdgcn_mfma_f32_16x16x32_bf16(af[0], bfr[nt][0], acc, 0, 0, 0);
            acc = __builtin_amdgcn_mfma_f32_16x16x32_bf16(af[1], bfr[nt][1], acc, 0, 0, 0);
            size_t base = ((size_t)bh * 1024 + p0 + lq * 4) * 64 + nt * 16 + lm;
#pragma unroll
            for (int r = 0; r < 4; r++)
                xw[base + (size_t)r * 64] = f2bf(acc[r] * 0.125f);
        }
    }
}

// ---------------------------------------------------------------------------
// Kernel 2: vt[b,h,d,p] = (x @ wv_w^T + wv_b) transposed (bf16).
// m97-style: global_load_lds width-16 into unpadded [128][32] LDS, BK=32.
// ---------------------------------------------------------------------------
__global__ __launch_bounds__(256) void vx_gemm(const short* __restrict__ xbf,
                                               const short* __restrict__ wvwb,
                                               const float* __restrict__ wvb,
                                               short* __restrict__ vt) {
    int mblk = blockIdx.x >> 3, nblk = blockIdx.x & 7;
    int m0 = mblk * 128, n0 = nblk * 128;
    __shared__ short As[128 * 32];
    __shared__ short Bs[128 * 32];

    int tid = threadIdx.x;
    int wv = tid >> 6, ln = tid & 63;
    int c0 = wv * 2;
    int rrow = ln >> 2, rseg = (ln & 3) * 8;
    const short* gA = xbf + (size_t)(m0 + c0 * 16 + rrow) * 1024 + rseg;
    const short* gB = wvwb + (size_t)(n0 + c0 * 16 + rrow) * 1024 + rseg;
    short* lA = As + c0 * 512;
    short* lB = Bs + c0 * 512;

    int lm = ln & 15, lq = ln >> 4;
    int wm = (wv >> 1) * 64, wn = (wv & 1) * 64;

    f32x4 acc[4][4];
#pragma unroll
    for (int i = 0; i < 4; i++)
#pragma unroll
        for (int j = 0; j < 4; j++) acc[i][j] = (f32x4){0.f, 0.f, 0.f, 0.f};

    for (int k0 = 0; k0 < 1024; k0 += 32) {
        __syncthreads();
        async16(gA + k0, lA);
        async16(gA + k0 + 16 * 1024, lA + 512);
        async16(gB + k0, lB);
        async16(gB + k0 + 16 * 1024, lB + 512);
        __syncthreads();
        bf16x8 af[4], bfr[4];
#pragma unroll
        for (int mt = 0; mt < 4; mt++) af[mt] = *(const bf16x8*)&As[(wm + mt * 16 + lm) * 32 + lq * 8];
#pragma unroll
        for (int nt = 0; nt < 4; nt++) bfr[nt] = *(const bf16x8*)&Bs[(wn + nt * 16 + lm) * 32 + lq * 8];
#pragma unroll
        for (int mt = 0; mt < 4; mt++)
#pragma unroll
            for (int nt = 0; nt < 4; nt++)
                acc[mt][nt] = __builtin_amdgcn_mfma_f32_16x16x32_bf16(af[mt], bfr[nt], acc[mt][nt], 0, 0, 0);
    }

#pragma unroll
    for (int nt = 0; nt < 4; nt++) {
        int e = n0 + wn + nt * 16 + lm;
        float bias = wvb[e];
        int hh = e >> 6, dd = e & 63;
#pragma unroll
        for (int mt = 0; mt < 4; mt++) {
            int pg = m0 + wm + mt * 16 + lq * 4;
            int bb = pg >> 10, pp = pg & 1023;
            bf16x4 pk;
#pragma unroll
            for (int r = 0; r < 4; r++) pk[r] = f2bf(acc[mt][nt][r] + bias);
            *(bf16x4*)(vt + ((size_t)((bb * 16 + hh) * 64 + dd)) * 1024 + pp) = pk;
        }
    }
}

// ---------------------------------------------------------------------------
// Kernel 3: flash attention v4 — transposed formulation, P stays in registers.
//   S^T = K·Q^T  (16x16x32; Q frags serve as B-operand unchanged)
//   P^T = exp(S^T)  — C/D layout of S^T == B-frag layout of 16x16x16 MFMA
//   O^T = V^T·P^T   (16x16x16; V^T A-frags are contiguous LDS reads)
// No Ps LDS, no bias transpose, double-buffered K/V, 1 barrier per tile.
// ---------------------------------------------------------------------------
__global__ __launch_bounds__(256, 4) void flash_kernel(const short* __restrict__ xbf,
                                                       const short* __restrict__ xw,
                                                       const short* __restrict__ vt,
                                                       const short* __restrict__ biasB,
                                                       short* __restrict__ obuf) {
    int bid = blockIdx.x;
    int qblk = bid & 7, b = (bid >> 3) & 15, h = bid >> 7;
    int bh = b * 16 + h;
    int q0 = qblk * 128;

    __shared__ short Ks[2][64][72];    // K[kv][d]
    __shared__ short Vs[2][64][72];    // V^T[d][kv]

    int tid = threadIdx.x, wave = tid >> 6, lane = tid & 63;
    int lm = lane & 15, lq = lane >> 4;

    // Q as B-operand frags [nt][kf] (pre-scaled by 0.125): n=q=lm, k=d=kf*32+lq*8
    bf16x8 qb[2][2];
#pragma unroll
    for (int nt = 0; nt < 2; nt++)
#pragma unroll
        for (int kf = 0; kf < 2; kf++)
            qb[nt][kf] = *(const bf16x8*)(xw + ((size_t)bh * 1024 + q0 + wave * 32 + nt * 16 + lm) * 64 + kf * 32 + lq * 8);

    // O^T accumulators [dt][nt]: row d = dt*16+lq*4+r, col q = nt*16+lm
    f32x4 o[4][2];
#pragma unroll
    for (int dt = 0; dt < 4; dt++)
#pragma unroll
        for (int nt = 0; nt < 2; nt++) o[dt][nt] = (f32x4){0.f, 0.f, 0.f, 0.f};
    float rs[2] = {0.f, 0.f};

    // staging maps: thread stages 2x bf16x8 for K and 2 for V
    int ci0 = tid * 2, ci1 = tid * 2 + 1;
    int r0 = ci0 >> 3, s0 = (ci0 & 7) * 8;
    int r1 = ci1 >> 3, s1 = (ci1 & 7) * 8;
    const short* kg = xbf + ((size_t)(b * 1024)) * 1024 + h * 64;  // + (kv0+row)*1024 + seg
    const short* vg = vt + ((size_t)bh * 64) * 1024;               // + row*1024 + kv0 + seg
    // bias [h][q][kv]: lane's 4 S^T values are contiguous along kv
    const short* bql = biasB + ((size_t)h << 20) + (size_t)(q0 + wave * 32 + lm) * 1024;

    bf16x8 kr0, kr1, vr0, vr1;
    bf16x4 br[4][2];
    // tile 0 loads
    kr0 = *(const bf16x8*)(kg + (size_t)r0 * 1024 + s0);
    kr1 = *(const bf16x8*)(kg + (size_t)r1 * 1024 + s1);
    vr0 = *(const bf16x8*)(vg + (size_t)r0 * 1024 + s0);
    vr1 = *(const bf16x8*)(vg + (size_t)r1 * 1024 + s1);
#pragma unroll
    for (int mt = 0; mt < 4; mt++)
#pragma unroll
        for (int nt = 0; nt < 2; nt++)
            br[mt][nt] = *(const bf16x4*)(bql + (size_t)nt * 16 * 1024 + mt * 16 + lq * 4);
    *(bf16x8*)&Ks[0][r0][s0] = kr0;
    *(bf16x8*)&Ks[0][r1][s1] = kr1;
    *(bf16x8*)&Vs[0][r0][s0] = vr0;
    *(bf16x8*)&Vs[0][r1][s1] = vr1;

    for (int tile = 0; tile < 16; tile++) {
        int cb = tile & 1;
        __syncthreads();
        int kvn = tile * 64 + 64;
        if (tile < 15) {   // global prefetch of next K/V tile (overlaps whole tile compute)
            kr0 = *(const bf16x8*)(kg + (size_t)(kvn + r0) * 1024 + s0);
            kr1 = *(const bf16x8*)(kg + (size_t)(kvn + r1) * 1024 + s1);
            vr0 = *(const bf16x8*)(vg + (size_t)r0 * 1024 + kvn + s0);
            vr1 = *(const bf16x8*)(vg + (size_t)r1 * 1024 + kvn + s1);
        }

        // QK (S^T) + exp + pack, mt-outer to keep register peak low
        bf16x4 pb[4][2];
#pragma unroll
        for (int mt = 0; mt < 4; mt++) {
            f32x4 s2[2];
#pragma unroll
            for (int nt = 0; nt < 2; nt++) {
                bf16x4 bv = br[mt][nt];
                s2[nt] = (f32x4){bf2f(bv[0]), bf2f(bv[1]), bf2f(bv[2]), bf2f(bv[3])};
            }
#pragma unroll
            for (int kf = 0; kf < 2; kf++) {
                bf16x8 ka = *(const bf16x8*)&Ks[cb][mt * 16 + lm][kf * 32 + lq * 8];
#pragma unroll
                for (int nt = 0; nt < 2; nt++)
                    s2[nt] = __builtin_amdgcn_mfma_f32_16x16x32_bf16(ka, qb[nt][kf], s2[nt], 0, 0, 0);
            }
#pragma unroll
            for (int nt = 0; nt < 2; nt++) {
                float p0v = __expf(s2[nt][0]);
                float p1v = __expf(s2[nt][1]);
                float p2v = __expf(s2[nt][2]);
                float p3v = __expf(s2[nt][3]);
                rs[nt] += (p0v + p1v) + (p2v + p3v);
                bf16x4 pk = {f2bf(p0v), f2bf(p1v), f2bf(p2v), f2bf(p3v)};
                pb[mt][nt] = pk;
            }
        }

        // bias prefetch for next tile (after all br consumed)
        if (tile < 15) {
#pragma unroll
            for (int mt = 0; mt < 4; mt++)
#pragma unroll
                for (int nt = 0; nt < 2; nt++)
                    br[mt][nt] = *(const bf16x4*)(bql + (size_t)nt * 16 * 1024 + kvn + mt * 16 + lq * 4);
        }

        // O^T += V^T · P^T  (16x16x16, P^T straight from registers)
#pragma unroll
        for (int mt = 0; mt < 4; mt++) {
#pragma unroll
            for (int dt = 0; dt < 4; dt++) {
                bf16x4 va = *(const bf16x4*)&Vs[cb][dt * 16 + lm][mt * 16 + lq * 4];
#pragma unroll
                for (int nt = 0; nt < 2; nt++)
                    o[dt][nt] = __builtin_amdgcn_mfma_f32_16x16x16bf16_1k(va, pb[mt][nt], o[dt][nt], 0, 0, 0);
            }
        }

        // write prefetched tile into the other buffer (no barrier needed here)
        if (tile < 15) {
            int nb = cb ^ 1;
            *(bf16x8*)&Ks[nb][r0][s0] = kr0;
            *(bf16x8*)&Ks[nb][r1][s1] = kr1;
            *(bf16x8*)&Vs[nb][r0][s0] = vr0;
            *(bf16x8*)&Vs[nb][r1][s1] = vr1;
        }
    }

    // epilogue: reduce l over lq lanes, O^T /= l, packed bf16x4 stores
    float inv[2];
#pragma unroll
    for (int nt = 0; nt < 2; nt++) {
        float t = rs[nt];
        t += __shfl_xor(t, 16);
        t += __shfl_xor(t, 32);
        inv[nt] = 1.f / t;
    }
#pragma unroll
    for (int dt = 0; dt < 4; dt++)
#pragma unroll
        for (int nt = 0; nt < 2; nt++) {
            bf16x4 pk;
#pragma unroll
            for (int r = 0; r < 4; r++) pk[r] = f2bf(o[dt][nt][r] * inv[nt]);
            int p = q0 + wave * 32 + nt * 16 + lm;
            *(bf16x4*)(obuf + ((size_t)(b * 1024 + p)) * 1024 + h * 64 + dt * 16 + lq * 4) = pk;
        }
}

// ---------------------------------------------------------------------------
// Kernel 4: out = obuf @ out_w^T + out_b (fp32). m97-style staging.
// ---------------------------------------------------------------------------
__global__ __launch_bounds__(256) void out_gemm(const short* __restrict__ obuf,
                                                const short* __restrict__ outwb,
                                                const float* __restrict__ outb,
                                                float* __restrict__ out) {
    int mblk = blockIdx.x >> 3, nblk = blockIdx.x & 7;
    int m0 = mblk * 128, n0 = nblk * 128;
    __shared__ short As[128 * 32];
    __shared__ short Bs[128 * 32];

    int tid = threadIdx.x;
    int wv = tid >> 6, ln = tid & 63;
    int c0 = wv * 2;
    int rrow = ln >> 2, rseg = (ln & 3) * 8;
    const short* gA = obuf + (size_t)(m0 + c0 * 16 + rrow) * 1024 + rseg;
    const short* gB = outwb + (size_t)(n0 + c0 * 16 + rrow) * 1024 + rseg;
    short* lA = As + c0 * 512;
    short* lB = Bs + c0 * 512;

    int lm = ln & 15, lq = ln >> 4;
    int wm = (wv >> 1) * 64, wn = (wv & 1) * 64;

    f32x4 acc[4][4];
#pragma unroll
    for (int i = 0; i < 4; i++)
#pragma unroll
        for (int j = 0; j < 4; j++) acc[i][j] = (f32x4){0.f, 0.f, 0.f, 0.f};

    for (int k0 = 0; k0 < 1024; k0 += 32) {
        __syncthreads();
        async16(gA + k0, lA);
        async16(gA + k0 + 16 * 1024, lA + 512);
        async16(gB + k0, lB);
        async16(gB + k0 + 16 * 1024, lB + 512);
        __syncthreads();
        bf16x8 af[4], bfr[4];
#pragma unroll
        for (int mt = 0; mt < 4; mt++) af[mt] = *(const bf16x8*)&As[(wm + mt * 16 + lm) * 32 + lq * 8];
#pragma unroll
        for (int nt = 0; nt < 4; nt++) bfr[nt] = *(const bf16x8*)&Bs[(wn + nt * 16 + lm) * 32 + lq * 8];
#pragma unroll
        for (int mt = 0; mt < 4; mt++)
#pragma unroll
            for (int nt = 0; nt < 4; nt++)
                acc[mt][nt] = __builtin_amdgcn_mfma_f32_16x16x32_bf16(af[mt], bfr[nt], acc[mt][nt], 0, 0, 0);
    }

#pragma unroll
    for (int nt = 0; nt < 4; nt++) {
        int e = n0 + wn + nt * 16 + lm;
        float bias = outb[e];
#pragma unroll
        for (int mt = 0; mt < 4; mt++) {
            int pg = m0 + wm + mt * 16 + lq * 4;
#pragma unroll
            for (int r = 0; r < 4; r++)
                out[(size_t)(pg + r) * 1024 + e] = acc[mt][nt][r] + bias;
        }
    }
}

extern "C" void kernel_launch(void* const* d_in, const int* in_sizes, int n_in,
                              void* d_out, int out_size, void* d_ws, size_t ws_size,
                              hipStream_t stream) {
    const float* x    = (const float*)d_in[0];  // [16,1024,1024]
    const float* watt = (const float*)d_in[1];  // [16,64,64]
    const float* bias = (const float*)d_in[2];  // [16,1024,1024]
    const float* wvw  = (const float*)d_in[3];  // [1024,1024]
    const float* wvb  = (const float*)d_in[4];  // [1024]
    const float* outw = (const float*)d_in[5];  // [1024,1024]
    const float* outb = (const float*)d_in[6];  // [1024]
    float* out = (float*)d_out;

    char* ws = (char*)d_ws;
    short* xw    = (short*)ws;                           // 32 MB  [B,H,P,DH] bf16 (Q, pre-scaled)
    short* vt    = (short*)(ws + ((size_t)32 << 20));    // 32 MB  [B,H,DH,P] bf16 (V^T)
    short* obuf  = (short*)(ws + ((size_t)64 << 20));    // 32 MB  [B,P,E]    bf16 (attn out)
    short* biasB = (short*)(ws + ((size_t)96 << 20));    // 32 MB  [H,P,P]    bf16 (bias, original order)
    short* xbf   = (short*)(ws + ((size_t)128 << 20));   // 32 MB  [B,P,E]    bf16 (x)
    short* wvwb  = (short*)(ws + ((size_t)160 << 20));   // 2 MB
    short* outwb = (short*)(ws + ((size_t)162 << 20));   // 2 MB

    conv_all<<<9216, 256, 0, stream>>>(bias, wvw, outw, biasB, wvwb, outwb);
    xw_kernel<<<PB * PH * 4, 256, 0, stream>>>(x, watt, xw, xbf);
    vx_gemm<<<(PB * PP / 128) * (PE / 128), 256, 0, stream>>>(xbf, wvwb, wvb, vt);
    flash_kernel<<<PB * PH * (PP / 128), 256, 0, stream>>>(xbf, xw, vt, biasB, obuf);
    out_gemm<<<(PB * PP / 128) * (PE / 128), 256, 0, stream>>>(obuf, outwb, outb, out);
}